// Round 6
// baseline (128.142 us; speedup 1.0000x reference)
//
#include <hip/hip_runtime.h>
#include <hip/hip_bf16.h>

#define BATCH 4096
#define IN_DIM 3072
#define HID 1024
#define NSTEP 8

typedef __attribute__((ext_vector_type(8))) short short8;
typedef __attribute__((ext_vector_type(4))) float f32x4;
typedef __attribute__((ext_vector_type(4))) unsigned short ushort4v;

__device__ __forceinline__ void gload_lds16(const void* g, void* lds) {
  __builtin_amdgcn_global_load_lds(
      (const __attribute__((address_space(1))) void*)g,
      (__attribute__((address_space(3))) void*)lds, 16, 0, 0);
}

__device__ __forceinline__ unsigned short f32_to_bf16(float f) {
  unsigned int u = __builtin_bit_cast(unsigned int, f);
  unsigned int r = u + 0x7fffu + ((u >> 16) & 1u);
  return (unsigned short)(r >> 16);
}

// XOR swizzle of the 16B-granule index within a row. KG=8 (BK=64): proven
// row&7 (0 conflicts measured). KG=4 (BK=32): (row^(row>>2))&3 -> worst-case
// 2-way bank aliasing on 16-row fragment reads (2-way is free, m136).
template <int KG>
__device__ __forceinline__ int swz_g(int row, int g) {
  if (KG == 8) return g ^ (row & 7);
  return g ^ ((row ^ (row >> 2)) & 3);
}

// fused f32 -> bf16 conversion of x, We, Wd (one launch)
__global__ void cvt3_kernel(const float* __restrict__ a,
                            const float* __restrict__ b,
                            const float* __restrict__ c,
                            unsigned short* __restrict__ da,
                            unsigned short* __restrict__ db,
                            unsigned short* __restrict__ dc, int na, int nb,
                            int nc) {
  const int total = na + nb + nc;
  const int stride = gridDim.x * blockDim.x;
  for (int i = blockIdx.x * blockDim.x + threadIdx.x; i < total; i += stride) {
    const float* s;
    unsigned short* d;
    int j = i;
    if (j < na) {
      s = a; d = da;
    } else if (j < na + nb) {
      s = b; d = db; j -= na;
    } else {
      s = c; d = dc; j -= na + nb;
    }
    const float4 v = reinterpret_cast<const float4*>(s)[j];
    ushort4v o;
    o.x = f32_to_bf16(v.x);
    o.y = f32_to_bf16(v.y);
    o.z = f32_to_bf16(v.z);
    o.w = f32_to_bf16(v.w);
    reinterpret_cast<ushort4v*>(d)[j] = o;
  }
}

// RK4 nmODE integrator (gamma already includes bias). In-place y over gamma
// (nontemporal: never re-read), bf16 copy for GEMM2 (cached).
__global__ __launch_bounds__(256) void ode_kernel(
    const float* __restrict__ gamma, float* __restrict__ hid,
    unsigned short* __restrict__ hb, int n4) {
  const float dt = 1.0f / (float)NSTEP;
  const float h2 = 0.5f * dt, hd = dt, h6 = dt / 6.0f;
  int stride = gridDim.x * blockDim.x;
  for (int i = blockIdx.x * blockDim.x + threadIdx.x; i < n4; i += stride) {
    const float4 g4 = reinterpret_cast<const float4*>(gamma)[i];
    float g[4] = {g4.x, g4.y, g4.z, g4.w};
    float y[4] = {0.0f, 0.0f, 0.0f, 0.0f};
#pragma unroll 1
    for (int s = 0; s < NSTEP; ++s) {
      float k1[4], k2[4], k3[4], k4[4];
#pragma unroll
      for (int e = 0; e < 4; ++e) {
        float t = __sinf(y[e] + g[e]);
        k1[e] = t * t - y[e];
      }
#pragma unroll
      for (int e = 0; e < 4; ++e) {
        float yy = fmaf(h2, k1[e], y[e]);
        float t = __sinf(yy + g[e]);
        k2[e] = t * t - yy;
      }
#pragma unroll
      for (int e = 0; e < 4; ++e) {
        float yy = fmaf(h2, k2[e], y[e]);
        float t = __sinf(yy + g[e]);
        k3[e] = t * t - yy;
      }
#pragma unroll
      for (int e = 0; e < 4; ++e) {
        float yy = fmaf(hd, k3[e], y[e]);
        float t = __sinf(yy + g[e]);
        k4[e] = t * t - yy;
      }
#pragma unroll
      for (int e = 0; e < 4; ++e) {
        float ks = k1[e] + 2.0f * (k2[e] + k3[e]) + k4[e];
        y[e] = fmaf(h6, ks, y[e]);
      }
    }
    f32x4 o4;
    o4[0] = y[0]; o4[1] = y[1]; o4[2] = y[2]; o4[3] = y[3];
    __builtin_nontemporal_store(o4, &reinterpret_cast<f32x4*>(hid)[i]);
    ushort4v ob;
    ob.x = f32_to_bf16(y[0]);
    ob.y = f32_to_bf16(y[1]);
    ob.z = f32_to_bf16(y[2]);
    ob.w = f32_to_bf16(y[3]);
    reinterpret_cast<ushort4v*>(hb)[i] = ob;
  }
}

// NT GEMM: C[M,N] = A[M,K] * B[N,K]^T + bias.
// BMxBN tile, BK-step, 4 waves (2x2), double-buffered LDS, XOR-swizzled
// (rule #21: linear gload_lds dest + inverse-swizzled global source +
// swizzled ds_read). 1-D grid, chunked XCD swizzle, bn-fastest decode.
// EPI=0: bias + raw f32 nontemporal store. EPI=1: bias + sigmoid nt store.
template <int BM, int BN, int BK, int EPI>
__global__ __launch_bounds__(256) void gemm_nt(
    const unsigned short* __restrict__ A, const unsigned short* __restrict__ B,
    const float* __restrict__ bias, float* __restrict__ Cout, int K, int Nout,
    int nbm, int nbn) {
  constexpr int WTM = BM / 2;         // wave tile rows
  constexpr int WTN = BN / 2;         // wave tile cols
  constexpr int AM = WTM / 16;        // acc frags m
  constexpr int AN = WTN / 16;        // acc frags n
  constexpr int KK = BK / 32;         // mfma k-steps per tile
  constexpr int KG = BK / 8;          // 16B granules per row
  constexpr int UA = BM * KG;         // short8 units in A tile (mult of 256)
  constexpr int UB = BN * KG;         // short8 units in B tile
  constexpr int NU = (UA + UB) / 256; // loads per thread per tile

  __shared__ unsigned short As[2][BM * BK];
  __shared__ unsigned short Bs[2][BN * BK];

  const int tid = threadIdx.x;
  const int wave = tid >> 6;
  const int lane = tid & 63;
  const int wrow = wave >> 1, wcol = wave & 1;

  // chunked XCD swizzle (grid divisible by 8), bn-fastest decode
  const int nwg = gridDim.x;
  const int swz = (blockIdx.x & 7) * (nwg >> 3) + (blockIdx.x >> 3);
  const int bn = swz % nbn;
  const int bm = swz / nbn;

  const unsigned short* Ablk = A + (size_t)bm * BM * K;
  const unsigned short* Bblk = B + (size_t)bn * BN * K;

  auto STAGE = [&](int buf, int k0) {
#pragma unroll
    for (int i = 0; i < NU; ++i) {
      const int u = i * 256 + tid;             // per-lane unit
      const int ubase = i * 256 + wave * 64;   // wave-uniform LDS base unit
      if (ubase < UA) {
        const int row = u / KG;
        const int g = swz_g<KG>(row, u % KG);  // inverse-swizzled source
        gload_lds16(Ablk + (size_t)row * K + k0 + g * 8,
                    (void*)&As[buf][ubase * 8]);
      } else {
        const int ub = u - UA;
        const int row = ub / KG;
        const int g = swz_g<KG>(row, ub % KG);
        gload_lds16(Bblk + (size_t)row * K + k0 + g * 8,
                    (void*)&Bs[buf][(ubase - UA) * 8]);
      }
    }
  };

  f32x4 acc[AM][AN] = {};
  const int fr = lane & 15;
  const int hi = lane >> 4;

  const int nt = K / BK;
  STAGE(0, 0);
  for (int t = 0; t < nt; ++t) {
    const int buf = t & 1;
    __syncthreads();  // implicit vmcnt(0): staged tile t resident
    if (t + 1 < nt) STAGE(buf ^ 1, (t + 1) * BK);

    short8 af[AM][KK], bfr[AN][KK];
#pragma unroll
    for (int m = 0; m < AM; ++m) {
      const int row = wrow * WTM + m * 16 + fr;
#pragma unroll
      for (int kk = 0; kk < KK; ++kk) {
        const int g = swz_g<KG>(row, kk * 4 + hi);  // swizzled read granule
        af[m][kk] =
            *reinterpret_cast<const short8*>(&As[buf][row * BK + g * 8]);
      }
    }
#pragma unroll
    for (int n = 0; n < AN; ++n) {
      const int row = wcol * WTN + n * 16 + fr;
#pragma unroll
      for (int kk = 0; kk < KK; ++kk) {
        const int g = swz_g<KG>(row, kk * 4 + hi);
        bfr[n][kk] =
            *reinterpret_cast<const short8*>(&Bs[buf][row * BK + g * 8]);
      }
    }
#pragma unroll
    for (int kk = 0; kk < KK; ++kk)
#pragma unroll
      for (int m = 0; m < AM; ++m)
#pragma unroll
        for (int n = 0; n < AN; ++n)
          acc[m][n] = __builtin_amdgcn_mfma_f32_16x16x32_bf16(
              af[m][kk], bfr[n][kk], acc[m][n], 0, 0, 0);
  }

  // epilogue: C/D layout col=lane&15, row=(lane>>4)*4+reg (m89-verified)
  const int rquad = hi * 4;
  const int colbase = bn * BN + wcol * WTN + fr;
  const int rowbase = bm * BM + wrow * WTM + rquad;

#pragma unroll
  for (int n = 0; n < AN; ++n) {
    const float bv = bias[colbase + n * 16];
#pragma unroll
    for (int m = 0; m < AM; ++m)
#pragma unroll
      for (int r = 0; r < 4; ++r) {
        float v = acc[m][n][r] + bv;
        if (EPI == 1) v = 1.0f / (1.0f + __expf(-v));
        size_t idx = (size_t)(rowbase + m * 16 + r) * Nout + (colbase + n * 16);
        __builtin_nontemporal_store(v, &Cout[idx]);
      }
  }
}

extern "C" void kernel_launch(void* const* d_in, const int* in_sizes, int n_in,
                              void* d_out, int out_size, void* d_ws,
                              size_t ws_size, hipStream_t stream) {
  const float* x = (const float*)d_in[0];
  const float* We = (const float*)d_in[1];
  const float* be = (const float*)d_in[2];
  const float* Wd = (const float*)d_in[3];
  const float* bd = (const float*)d_in[4];

  float* out = (float*)d_out;                   // [4096,3072]
  float* hid = out + (size_t)BATCH * IN_DIM;    // [4096,1024] (gamma, then y)

  unsigned short* xb = (unsigned short*)d_ws;          // bf16 x   [4096,3072]
  unsigned short* Web = xb + (size_t)BATCH * IN_DIM;   // bf16 We  [1024,3072]
  unsigned short* Wdb = Web + (size_t)HID * IN_DIM;    // bf16 Wd  [3072,1024]
  unsigned short* hb = Wdb + (size_t)IN_DIM * HID;     // bf16 hid [4096,1024]

  cvt3_kernel<<<2048, 256, 0, stream>>>(
      x, We, Wd, xb, Web, Wdb, BATCH * IN_DIM / 4, HID * IN_DIM / 4,
      IN_DIM * HID / 4);

  // GEMM1: gamma = x @ We^T + be -> hid region. 128x64, BK=64,
  // grid 32x16=512 = exactly 2 blocks/CU (48 KB LDS), no tail wave.
  gemm_nt<128, 64, 64, 0><<<512, 256, 0, stream>>>(xb, Web, be, hid, IN_DIM,
                                                   HID, BATCH / 128, HID / 64);

  // ODE: y(1) from gamma (in place, nt store); bf16 copy to hb
  ode_kernel<<<2048, 256, 0, stream>>>(hid, hid, hb, BATCH * HID / 4);

  // GEMM2: out = sigmoid(y @ Wd^T + bd). 128x192, BK=32,
  // grid 32x16=512 = exactly 2 blocks/CU (40 KB LDS), no tail wave.
  gemm_nt<128, 192, 32, 1><<<512, 256, 0, stream>>>(
      hb, Wdb, bd, out, HID, IN_DIM, BATCH / 128, IN_DIM / 192);
}

// Round 8
// 117.842 us; speedup vs baseline: 1.0874x; 1.0874x over previous
//
#include <hip/hip_runtime.h>
#include <hip/hip_bf16.h>

#define BATCH 4096
#define IN_DIM 3072
#define HID 1024
#define NSTEP 8

typedef __attribute__((ext_vector_type(8))) short short8;
typedef __attribute__((ext_vector_type(4))) float f32x4;
typedef __attribute__((ext_vector_type(4))) unsigned short ushort4v;

__device__ __forceinline__ void gload_lds16(const void* g, void* lds) {
  __builtin_amdgcn_global_load_lds(
      (const __attribute__((address_space(1))) void*)g,
      (__attribute__((address_space(3))) void*)lds, 16, 0, 0);
}

__device__ __forceinline__ unsigned short f32_to_bf16(float f) {
  unsigned int u = __builtin_bit_cast(unsigned int, f);
  unsigned int r = u + 0x7fffu + ((u >> 16) & 1u);
  return (unsigned short)(r >> 16);
}

// compiler-motion fence + HW barrier + scheduler pin
#define BARX()                          \
  do {                                  \
    asm volatile("" ::: "memory");      \
    __builtin_amdgcn_s_barrier();       \
    __builtin_amdgcn_sched_barrier(0);  \
  } while (0)

#define LGKM0()                                        \
  do {                                                 \
    asm volatile("s_waitcnt lgkmcnt(0)" ::: "memory"); \
    __builtin_amdgcn_sched_barrier(0);                 \
  } while (0)

// fused f32 -> bf16 conversion of x, We, Wd (one launch)
__global__ void cvt3_kernel(const float* __restrict__ a,
                            const float* __restrict__ b,
                            const float* __restrict__ c,
                            unsigned short* __restrict__ da,
                            unsigned short* __restrict__ db,
                            unsigned short* __restrict__ dc, int na, int nb,
                            int nc) {
  const int total = na + nb + nc;
  const int stride = gridDim.x * blockDim.x;
  for (int i = blockIdx.x * blockDim.x + threadIdx.x; i < total; i += stride) {
    const float* s;
    unsigned short* d;
    int j = i;
    if (j < na) {
      s = a; d = da;
    } else if (j < na + nb) {
      s = b; d = db; j -= na;
    } else {
      s = c; d = dc; j -= na + nb;
    }
    const float4 v = reinterpret_cast<const float4*>(s)[j];
    ushort4v o;
    o.x = f32_to_bf16(v.x);
    o.y = f32_to_bf16(v.y);
    o.z = f32_to_bf16(v.z);
    o.w = f32_to_bf16(v.w);
    reinterpret_cast<ushort4v*>(d)[j] = o;
  }
}

// 4-way split-K reduce + bias + RK4 nmODE. part = 4 stacked [4096,1024] f32
// partials (p3 occupies the hid region of d_out; thread i reads p3[i] before
// writing y[i] to the same address -> safe). Writes y f32 (NT) + bf16.
__global__ __launch_bounds__(256) void ode4_kernel(
    const float* __restrict__ part, const float* __restrict__ be,
    float* __restrict__ hid, unsigned short* __restrict__ hb, int n4) {
  const float dt = 1.0f / (float)NSTEP;
  const float h2 = 0.5f * dt, hd = dt, h6 = dt / 6.0f;
  const size_t seg = (size_t)BATCH * HID / 4;  // float4 units per partial
  const float4* p4 = reinterpret_cast<const float4*>(part);
  int stride = gridDim.x * blockDim.x;
  for (int i = blockIdx.x * blockDim.x + threadIdx.x; i < n4; i += stride) {
    const float4 a4 = p4[i];
    const float4 b4 = p4[i + seg];
    const float4 c4 = p4[i + 2 * seg];
    const float4 d4 = p4[i + 3 * seg];
    const float4 e4 = reinterpret_cast<const float4*>(be)[i & (HID / 4 - 1)];
    float g[4] = {a4.x + b4.x + c4.x + d4.x + e4.x,
                  a4.y + b4.y + c4.y + d4.y + e4.y,
                  a4.z + b4.z + c4.z + d4.z + e4.z,
                  a4.w + b4.w + c4.w + d4.w + e4.w};
    float y[4] = {0.0f, 0.0f, 0.0f, 0.0f};
#pragma unroll 1
    for (int s = 0; s < NSTEP; ++s) {
      float k1[4], k2[4], k3[4], k4[4];
#pragma unroll
      for (int e = 0; e < 4; ++e) {
        float t = __sinf(y[e] + g[e]);
        k1[e] = t * t - y[e];
      }
#pragma unroll
      for (int e = 0; e < 4; ++e) {
        float yy = fmaf(h2, k1[e], y[e]);
        float t = __sinf(yy + g[e]);
        k2[e] = t * t - yy;
      }
#pragma unroll
      for (int e = 0; e < 4; ++e) {
        float yy = fmaf(h2, k2[e], y[e]);
        float t = __sinf(yy + g[e]);
        k3[e] = t * t - yy;
      }
#pragma unroll
      for (int e = 0; e < 4; ++e) {
        float yy = fmaf(hd, k3[e], y[e]);
        float t = __sinf(yy + g[e]);
        k4[e] = t * t - yy;
      }
#pragma unroll
      for (int e = 0; e < 4; ++e) {
        float ks = k1[e] + 2.0f * (k2[e] + k3[e]) + k4[e];
        y[e] = fmaf(h6, ks, y[e]);
      }
    }
    f32x4 o4;
    o4[0] = y[0]; o4[1] = y[1]; o4[2] = y[2]; o4[3] = y[3];
    __builtin_nontemporal_store(o4, &reinterpret_cast<f32x4*>(hid)[i]);
    ushort4v ob;
    ob.x = f32_to_bf16(y[0]);
    ob.y = f32_to_bf16(y[1]);
    ob.z = f32_to_bf16(y[2]);
    ob.w = f32_to_bf16(y[3]);
    reinterpret_cast<ushort4v*>(hb)[i] = ob;
  }
}

// 8-phase NT GEMM (m201-style): C[M,N] = A[M,K]*B[N,K]^T (+bias/sigmoid).
// BM=256 x BN tile, BK=64, 8 waves (2 row x 4 col), per-wave 128 x BN/4.
// Register-lean per-phase fragment reads (spill-free, keeps vmcnt contract):
// per tile: ph1 A0+B1 -> A0*B1; ph2 B2 -> A0*B2; ph3 A1 -> A1*B2;
// ph4 -> A1*B1 (B1 still resident). Counted vmcnt only at ph4/ph8 (never 0
// in loop). Row&7 granule XOR swizzle (rule #21: linear gload_lds dest +
// inverse-swizzled global source + swizzled ds_read).
template <int BN, int NSK, int EPI>
__global__ __launch_bounds__(512, 2) void gemm8p(
    const unsigned short* __restrict__ A, const unsigned short* __restrict__ B,
    const float* __restrict__ bias, float* __restrict__ Cout, int Kstride,
    int Nout, int nbm, int nbn, int M) {
  constexpr int BM = 256, BK = 64;
  constexpr int CN = BN / 4;            // per-wave col extent (64 or 48)
  constexpr int AN = CN / 16;           // 4 or 3 acc frags n
  constexpr int NB2 = AN - 2;           // frags in B group 2 (2 or 1)
  constexpr int RB = BN / 64;           // B stage rounds (4 or 3)
  constexpr int R = 4 + RB;             // stage rounds per K-tile (8 or 7)
  constexpr int VM = (R == 8) ? 2 : 1;  // rounds at ph4/ph8 = counted vmcnt

  __shared__ unsigned short As[2][BM * BK];
  __shared__ unsigned short Bs[2][BN * BK];

  const int tid = threadIdx.x;
  const int wave = tid >> 6;
  const int lane = tid & 63;
  const int wrow = wave >> 2;  // 0..1
  const int wcol = wave & 3;   // 0..3

  // chunked XCD swizzle (grid divisible by 8), bn-fastest, sk-slowest
  const int nwg = gridDim.x;
  const int swz = (blockIdx.x & 7) * (nwg >> 3) + (blockIdx.x >> 3);
  const int tiles = nbm * nbn;
  const int sk = swz / tiles;
  const int rem = swz % tiles;
  const int bn = rem % nbn;
  const int bm = rem / nbn;

  const int Klen = Kstride / NSK;
  const int ntT = Klen / BK;  // even (12 or 16)
  const unsigned short* Ablk = A + (size_t)bm * BM * Kstride + sk * Klen;
  const unsigned short* Bblk = B + (size_t)bn * BN * Kstride + sk * Klen;

  const int srr = tid >> 3;  // row within a 64-row stage round
  const int sgl = tid & 7;   // linear 16B granule

  auto STAGE = [&](int buf, int k0, int r) {
    if (r < 4) {
      const int row = r * 64 + srr;
      const int g = sgl ^ (row & 7);  // inverse-swizzled global source
      gload_lds16(Ablk + (size_t)row * Kstride + k0 + g * 8,
                  (void*)&As[buf][r * 4096 + wave * 512]);
    } else {
      const int row = (r - 4) * 64 + srr;
      const int g = sgl ^ (row & 7);
      gload_lds16(Bblk + (size_t)row * Kstride + k0 + g * 8,
                  (void*)&Bs[buf][(r - 4) * 4096 + wave * 512]);
    }
  };

  auto VMW = [&]() {
    if constexpr (VM == 2)
      asm volatile("s_waitcnt vmcnt(2)" ::: "memory");
    else
      asm volatile("s_waitcnt vmcnt(1)" ::: "memory");
  };

  const int fr = lane & 15;
  const int hi = lane >> 4;

  short8 a[4][2], b1[2][2], b2[NB2][2];
  f32x4 acc[8][AN] = {};

  auto READ_A = [&](int buf, int mh) {
#pragma unroll
    for (int m = 0; m < 4; ++m) {
      const int row = wrow * 128 + (mh * 4 + m) * 16 + fr;
#pragma unroll
      for (int kk = 0; kk < 2; ++kk) {
        const int g = (kk * 4 + hi) ^ (row & 7);
        a[m][kk] =
            *reinterpret_cast<const short8*>(&As[buf][row * BK + g * 8]);
      }
    }
  };
  auto READ_B1 = [&](int buf) {
#pragma unroll
    for (int n = 0; n < 2; ++n) {
      const int row = wcol * CN + n * 16 + fr;
#pragma unroll
      for (int kk = 0; kk < 2; ++kk) {
        const int g = (kk * 4 + hi) ^ (row & 7);
        b1[n][kk] =
            *reinterpret_cast<const short8*>(&Bs[buf][row * BK + g * 8]);
      }
    }
  };
  auto READ_B2 = [&](int buf) {
#pragma unroll
    for (int j = 0; j < NB2; ++j) {
      const int row = wcol * CN + (2 + j) * 16 + fr;
#pragma unroll
      for (int kk = 0; kk < 2; ++kk) {
        const int g = (kk * 4 + hi) ^ (row & 7);
        b2[j][kk] =
            *reinterpret_cast<const short8*>(&Bs[buf][row * BK + g * 8]);
      }
    }
  };
  auto MM_B1 = [&](int mh) {
#pragma unroll
    for (int kk = 0; kk < 2; ++kk)
#pragma unroll
      for (int m = 0; m < 4; ++m)
#pragma unroll
        for (int n = 0; n < 2; ++n)
          acc[mh * 4 + m][n] = __builtin_amdgcn_mfma_f32_16x16x32_bf16(
              a[m][kk], b1[n][kk], acc[mh * 4 + m][n], 0, 0, 0);
  };
  auto MM_B2 = [&](int mh) {
#pragma unroll
    for (int kk = 0; kk < 2; ++kk)
#pragma unroll
      for (int m = 0; m < 4; ++m)
#pragma unroll
        for (int j = 0; j < NB2; ++j)
          acc[mh * 4 + m][2 + j] = __builtin_amdgcn_mfma_f32_16x16x32_bf16(
              a[m][kk], b2[j][kk], acc[mh * 4 + m][2 + j], 0, 0, 0);
  };

  // one K-tile (4 phases) from buffer b; stages rounds VM..VM+5 of the NEXT
  // tile (kn -> buf b^1) in ph1-3 and rounds 0..VM-1 of tile kn2 (-> buf b)
  // in ph4 with the counted vmcnt.
  auto HALF = [&](int b, int kn, int kn2) {
    // ph1
    READ_A(b, 0);
    READ_B1(b);
    STAGE(b ^ 1, kn, VM + 0); STAGE(b ^ 1, kn, VM + 1);
    BARX(); LGKM0();
    __builtin_amdgcn_s_setprio(1); MM_B1(0);
    __builtin_amdgcn_s_setprio(0); BARX();
    // ph2
    READ_B2(b);
    STAGE(b ^ 1, kn, VM + 2); STAGE(b ^ 1, kn, VM + 3);
    BARX(); LGKM0();
    __builtin_amdgcn_s_setprio(1); MM_B2(0);
    __builtin_amdgcn_s_setprio(0); BARX();
    // ph3
    READ_A(b, 1);
    STAGE(b ^ 1, kn, VM + 4); STAGE(b ^ 1, kn, VM + 5);
    BARX(); LGKM0();
    __builtin_amdgcn_s_setprio(1); MM_B2(1);
    __builtin_amdgcn_s_setprio(0); BARX();
    // ph4: begin restaging THIS buffer's successor; counted wait publishes
    // the next tile (kn) as fully resident in buf b^1.
    STAGE(b, kn2, 0);
    if constexpr (VM == 2) STAGE(b, kn2, 1);
    VMW();
    BARX();
    __builtin_amdgcn_s_setprio(1); MM_B1(1);
    __builtin_amdgcn_s_setprio(0); BARX();
  };

  // prologue: tile 0 fully + first VM rounds of tile 1; wait tile 0 resident
#pragma unroll
  for (int r = 0; r < R; ++r) STAGE(0, 0, r);
  STAGE(1, BK, 0);
  if constexpr (VM == 2) STAGE(1, BK, 1);
  VMW();
  BARX();

#pragma unroll 1
  for (int it = 0; it < ntT / 2; ++it) {
    const int t0 = 2 * it;
    const int k1 = (t0 + 1) * BK;
    const int k2 = ((t0 + 2 == ntT) ? 0 : t0 + 2) * BK;
    const int k3 = ((t0 + 3 >= ntT) ? t0 + 3 - ntT : t0 + 3) * BK;
    HALF(0, k1, k2);
    HALF(1, k2, k3);
  }

  // epilogue: C/D layout col=lane&15, row=(lane>>4)*4+reg (m89-verified)
  const int rowbase = bm * BM + wrow * 128 + hi * 4;
  const int colbase = bn * BN + wcol * CN + fr;
  float* Cblk = Cout + (size_t)sk * M * Nout;

#pragma unroll
  for (int m = 0; m < 8; ++m)
#pragma unroll
    for (int n = 0; n < AN; ++n) {
      float bv = 0.0f;
      if constexpr (EPI == 1) bv = bias[colbase + n * 16];
#pragma unroll
      for (int r = 0; r < 4; ++r) {
        float v = acc[m][n][r] + bv;
        size_t idx = (size_t)(rowbase + m * 16 + r) * Nout + (colbase + n * 16);
        if constexpr (EPI == 1) {
          v = 1.0f / (1.0f + __expf(-v));
          __builtin_nontemporal_store(v, &Cout[idx]);
        } else {
          Cblk[idx] = v;
        }
      }
    }
}

extern "C" void kernel_launch(void* const* d_in, const int* in_sizes, int n_in,
                              void* d_out, int out_size, void* d_ws,
                              size_t ws_size, hipStream_t stream) {
  const float* x = (const float*)d_in[0];
  const float* We = (const float*)d_in[1];
  const float* be = (const float*)d_in[2];
  const float* Wd = (const float*)d_in[3];
  const float* bd = (const float*)d_in[4];

  float* out = (float*)d_out;                 // [4096,3072]
  float* hid = out + (size_t)BATCH * IN_DIM;  // [4096,1024]
  // GEMM1 split-K=4 partials occupy ALL of d_out (4 x 16.78MB = 67.1MB);
  // p3 = hid region. ODE consumes partials, then GEMM2 overwrites p0-p2.
  float* part = out;

  unsigned short* xb = (unsigned short*)d_ws;          // bf16 x   [4096,3072]
  unsigned short* Web = xb + (size_t)BATCH * IN_DIM;   // bf16 We  [1024,3072]
  unsigned short* Wdb = Web + (size_t)HID * IN_DIM;    // bf16 Wd  [3072,1024]
  unsigned short* hb = Wdb + (size_t)IN_DIM * HID;     // bf16 hid [4096,1024]

  cvt3_kernel<<<2048, 256, 0, stream>>>(
      x, We, Wd, xb, Web, Wdb, BATCH * IN_DIM / 4, HID * IN_DIM / 4,
      IN_DIM * HID / 4);

  // GEMM1: partials of x @ We^T. 256x256, BK=64, split-K=4 -> 256 blocks.
  gemm8p<256, 4, 0><<<256, 512, 0, stream>>>(xb, Web, nullptr, part, IN_DIM,
                                             HID, BATCH / 256, HID / 256,
                                             BATCH);

  // ODE: gamma = p0+p1+p2+p3+be, RK4 -> hid f32 (NT) + hb bf16
  ode4_kernel<<<2048, 256, 0, stream>>>(part, be, hid, hb, BATCH * HID / 4);

  // GEMM2: out = sigmoid(y @ Wd^T + bd). 256x192 -> 16x16 = 256 blocks.
  gemm8p<192, 1, 1><<<256, 512, 0, stream>>>(hb, Wdb, bd, out, HID, IN_DIM,
                                             BATCH / 256, IN_DIM / 192, BATCH);
}